// Round 2
// baseline (390.767 us; speedup 1.0000x reference)
//
#include <hip/hip_runtime.h>
#include <hip/hip_bf16.h>

// MultiScaleFeatureExtractor on MI355X (gfx950) — Round 2
// Math restructuring (unchanged from R1):
//   logits = x @ (Wx@Wslice) + (bx@Wslice + bslice)      (px never materialized)
//   out[s,d] = (sum_n w[n,s]*fx[n,d]) / (sum_n w[n,s] + 0.01)
// R2 structure: weights held in REGISTERS (fragment order), x pre-converted to
// bf16 in MFMA A-fragment order by a pre-pass -> main has no staging LDS at all.
// LDS = wT/fT transpose buffers only (18.4 KB) -> 2 blocks/CU.
//
// Fast-path ws layout (needs 67,901,440 B; falls back to R1 path otherwise):
//   [0,        67108864)  xf   bf16 A-frags [tile(256)][chunk(8)][tw(4)][ks(8)][lane(64)][j(8)]
//   [67108864, 67633152)  WtF  bf16 B-frags [proj(2)][head(8)][nt(4)][ks(8)][lane(64)][j(8)]
//   [67633152, 67635200)  bc   f32 [512]
//   [67635200, 67897344)  Tg   f32 [B*8*64*64]
//   [67897344, 67901440)  ng   f32 [B*8*64]

typedef __attribute__((ext_vector_type(8))) short short8;
typedef __attribute__((ext_vector_type(4))) short short4v;
typedef __attribute__((ext_vector_type(4))) float float4v;

#define WPITCH 264   // v1 fallback LDS pitch
#define TPITCH 72    // wT/fT pitch (multiple of 8 shorts: 16B-aligned rows for b128)

__device__ __forceinline__ unsigned short f2bf(float f) {
    union { float f; unsigned int u; } v; v.f = f;
    unsigned int r = (v.u + 0x7FFFu + ((v.u >> 16) & 1u)) >> 16;  // RNE
    return (unsigned short)r;
}

// ================= Round-2 fast path =================

// ---- xprep: fp32 x -> bf16 A-fragment order. grid 2048 (tile*8+chunk) x 256.
__global__ void msfe_xprep(const float* __restrict__ x, unsigned short* __restrict__ xf) {
    const int blk  = blockIdx.x;          // tile*8 + chunk
    const int tid  = threadIdx.x;
    const int tw   = tid >> 6;            // wave = token sub-tile
    const int lane = tid & 63;
    const int quad = lane >> 4;
    const int l16  = lane & 15;
    const float* xrow = x + ((long)blk * 64 + tw * 16 + l16) * 256;
    unsigned short* ob = xf + (((long)blk * 4 + tw) * 8) * 512 + lane * 8;
    #pragma unroll
    for (int ks = 0; ks < 8; ++ks) {
        const float4v* p = (const float4v*)(xrow + ks * 32 + quad * 8);
        float4v v0 = p[0], v1 = p[1];
        short8 o;
        o[0] = (short)f2bf(v0.x); o[1] = (short)f2bf(v0.y);
        o[2] = (short)f2bf(v0.z); o[3] = (short)f2bf(v0.w);
        o[4] = (short)f2bf(v1.x); o[5] = (short)f2bf(v1.y);
        o[6] = (short)f2bf(v1.z); o[7] = (short)f2bf(v1.w);
        *(short8*)(ob + ks * 512) = o;    // 16B store, lane-contiguous: coalesced
    }
}

// ---- prep2: fold Wx@Wslice + reformat Wfx into B-fragment order; compute bc.
// grid 65 x 256. blocks 0..31 logits (head,nt), 32..63 fx (head,nt), 64 bc.
__global__ void msfe_prep2(const float* __restrict__ Wx, const float* __restrict__ bx,
                           const float* __restrict__ Wfx,
                           const float* __restrict__ Wslice, const float* __restrict__ bslice,
                           unsigned short* __restrict__ WtF, float* __restrict__ bcv) {
    const int b = blockIdx.x, tid = threadIdx.x;
    if (b < 64) {
        const int proj = b >> 5, hb = b & 31, head = hb >> 2, nt = hb & 3;
        #pragma unroll
        for (int p = 0; p < 2; ++p) {
            int idx = tid + p * 256;            // 0..511 = (ks, lane)
            int ks = idx >> 6, l = idx & 63;
            int quad = l >> 4, l16 = l & 15;
            unsigned short* out = WtF + ((((long)(proj * 8 + head) * 4 + nt) * 8 + ks) * 64 + l) * 8;
            if (proj == 0) {
                int s = nt * 16 + l16;
                #pragma unroll
                for (int j = 0; j < 8; ++j) {
                    int k = ks * 32 + quad * 8 + j;
                    const float* wr = Wx + k * 512 + head * 64;
                    float acc = 0.f;
                    #pragma unroll 8
                    for (int d = 0; d < 64; ++d)
                        acc += wr[d] * Wslice[d * 64 + s];
                    out[j] = f2bf(acc);
                }
            } else {
                int col = head * 64 + nt * 16 + l16;
                #pragma unroll
                for (int j = 0; j < 8; ++j) {
                    int k = ks * 32 + quad * 8 + j;
                    out[j] = f2bf(Wfx[k * 512 + col]);
                }
            }
        }
    } else {
        #pragma unroll
        for (int p = 0; p < 2; ++p) {
            int j = tid + p * 256;
            int h = j >> 6, s = j & 63;
            float bsum = bslice[s];
            for (int d = 0; d < 64; ++d) bsum += bx[h * 64 + d] * Wslice[d * 64 + s];
            bcv[j] = bsum;
        }
    }
}

// ---- main2: weights in registers, A-frags from global, LDS only for transpose.
__global__ __launch_bounds__(512, 2)
void msfe_main2(const unsigned short* __restrict__ xf,
                const unsigned short* __restrict__ WtF,
                const float* __restrict__ bcv,
                const float* __restrict__ bfx,
                const float* __restrict__ temperature,
                float* __restrict__ Tg, float* __restrict__ ng) {
    __shared__ unsigned short wT[64 * TPITCH];   // w transposed  [s][token]
    __shared__ unsigned short fT[64 * TPITCH];   // fx transposed [d][token]

    const int tid  = threadIdx.x;
    const int lane = tid & 63;
    const int wv   = tid >> 6;    // 0..7
    const int quad = lane >> 4;
    const int l16  = lane & 15;

    // blockIdx -> (round, xcd, tileInXcd, head): same-tile heads share an XCD round
    const int bidx = blockIdx.x;
    const int c8   = bidx & 7;
    const int ti   = (bidx >> 3) & 3;
    const int head = (bidx >> 5) & 7;
    const int rnd  = bidx >> 8;
    const int tile = rnd * 32 + c8 * 4 + ti;      // 0..255
    const int batch = tile >> 7;

    const int proj = wv >> 2;   // 0: logits+softmax waves, 1: fx waves
    const int tw   = wv & 3;    // P1 token sub-tile
    const int sh   = wv & 3;    // P3 s-tile
    const int dh   = wv >> 2;   // P3 d-half

    // ---- weight fragments -> registers (once per block, coalesced 1KB loads)
    short8 wfr[4][8];
    {
        const unsigned short* wb = WtF + (((long)(proj * 8 + head) * 4) * 8) * 512 + lane * 8;
        #pragma unroll
        for (int nt = 0; nt < 4; ++nt)
            #pragma unroll
            for (int ks = 0; ks < 8; ++ks)
                wfr[nt][ks] = *(const short8*)(wb + (nt * 8 + ks) * 512);
    }

    float bcr[4], bfxr[4];
    #pragma unroll
    for (int nt = 0; nt < 4; ++nt) {
        bcr[nt]  = bcv[head * 64 + nt * 16 + l16];
        bfxr[nt] = bfx[head * 64 + nt * 16 + l16];
    }
    float tmp = temperature[head];
    tmp = fminf(fmaxf(tmp, 0.5f), 5.0f);
    const float invt = 1.0f / tmp;

    float4v Tac[2];
    Tac[0] = (float4v){0.f, 0.f, 0.f, 0.f};
    Tac[1] = (float4v){0.f, 0.f, 0.f, 0.f};
    float normAcc[4] = {0.f, 0.f, 0.f, 0.f};

    // ---- A-frag preload chunk 0
    const unsigned short* xb = xf + ((long)tile * 8 * 4 * 8) * 512 + lane * 8;  // + ((c*4+tw)*8+ks)*512
    short8 afr[8];
    #pragma unroll
    for (int ks = 0; ks < 8; ++ks)
        afr[ks] = *(const short8*)(xb + ((0 * 4 + tw) * 8 + ks) * 512);

    for (int c = 0; c < 8; ++c) {
        // P1: [16 tok x 64 cols] += A(x) * B(weights-in-regs), K=256
        float4v acc[4];
        #pragma unroll
        for (int nt = 0; nt < 4; ++nt) acc[nt] = (float4v){0.f, 0.f, 0.f, 0.f};
        #pragma unroll
        for (int ks = 0; ks < 8; ++ks) {
            #pragma unroll
            for (int nt = 0; nt < 4; ++nt)
                acc[nt] = __builtin_amdgcn_mfma_f32_16x16x32_bf16(afr[ks], wfr[nt][ks], acc[nt], 0, 0, 0);
        }

        // prefetch next chunk's A-frags (latency hidden behind P2+barrier+P3)
        if (c < 7) {
            #pragma unroll
            for (int ks = 0; ks < 8; ++ks)
                afr[ks] = *(const short8*)(xb + (((c + 1) * 4 + tw) * 8 + ks) * 512);
        }

        // P2: softmax (proj 0) / bias (proj 1), write transposed bf16 to LDS.
        // C layout: col=l16+16*nt, row=quad*4+r -> token = 16*tw + quad*4 + r
        if (proj == 0) {
            float v[4][4];
            #pragma unroll
            for (int nt = 0; nt < 4; ++nt)
                #pragma unroll
                for (int r = 0; r < 4; ++r)
                    v[nt][r] = (acc[nt][r] + bcr[nt]) * invt;
            #pragma unroll
            for (int r = 0; r < 4; ++r) {
                float m = fmaxf(fmaxf(v[0][r], v[1][r]), fmaxf(v[2][r], v[3][r]));
                m = fmaxf(m, __shfl_xor(m, 1));
                m = fmaxf(m, __shfl_xor(m, 2));
                m = fmaxf(m, __shfl_xor(m, 4));
                m = fmaxf(m, __shfl_xor(m, 8));
                float e0 = __expf(v[0][r] - m), e1 = __expf(v[1][r] - m);
                float e2 = __expf(v[2][r] - m), e3 = __expf(v[3][r] - m);
                float s = e0 + e1 + e2 + e3;
                s += __shfl_xor(s, 1); s += __shfl_xor(s, 2);
                s += __shfl_xor(s, 4); s += __shfl_xor(s, 8);
                float inv = 1.0f / s;
                v[0][r] = e0 * inv; v[1][r] = e1 * inv; v[2][r] = e2 * inv; v[3][r] = e3 * inv;
            }
            #pragma unroll
            for (int nt = 0; nt < 4; ++nt) {
                normAcc[nt] += v[nt][0] + v[nt][1] + v[nt][2] + v[nt][3];
                short4v p;
                p.x = (short)f2bf(v[nt][0]); p.y = (short)f2bf(v[nt][1]);
                p.z = (short)f2bf(v[nt][2]); p.w = (short)f2bf(v[nt][3]);
                *(short4v*)(wT + (nt * 16 + l16) * TPITCH + tw * 16 + quad * 4) = p;
            }
        } else {
            #pragma unroll
            for (int nt = 0; nt < 4; ++nt) {
                short4v p;
                p.x = (short)f2bf(acc[nt][0] + bfxr[nt]);
                p.y = (short)f2bf(acc[nt][1] + bfxr[nt]);
                p.z = (short)f2bf(acc[nt][2] + bfxr[nt]);
                p.w = (short)f2bf(acc[nt][3] + bfxr[nt]);
                *(short4v*)(fT + (nt * 16 + l16) * TPITCH + tw * 16 + quad * 4) = p;
            }
        }

        __syncthreads();

        // P3: T[s][d] += w^T fx over 64 chunk tokens. wave: 16 s x 32 d.
        #pragma unroll
        for (int ks = 0; ks < 2; ++ks) {
            short8 a = *(const short8*)(wT + (sh * 16 + l16) * TPITCH + ks * 32 + quad * 8);
            #pragma unroll
            for (int nt = 0; nt < 2; ++nt) {
                short8 b = *(const short8*)(fT + (dh * 32 + nt * 16 + l16) * TPITCH + ks * 32 + quad * 8);
                Tac[nt] = __builtin_amdgcn_mfma_f32_16x16x32_bf16(a, b, Tac[nt], 0, 0, 0);
            }
        }

        __syncthreads();   // protect wT/fT reuse next chunk
    }

    // epilogue: atomics into global accumulators
    const int basehs = (batch * 8 + head) * 64;
    #pragma unroll
    for (int nt = 0; nt < 2; ++nt) {
        #pragma unroll
        for (int r = 0; r < 4; ++r) {
            int s = sh * 16 + quad * 4 + r;
            int d = dh * 32 + nt * 16 + l16;
            atomicAdd(&Tg[(basehs + s) * 64 + d], Tac[nt][r]);
        }
    }
    if (wv < 4) {
        #pragma unroll
        for (int nt = 0; nt < 4; ++nt) {
            float v = normAcc[nt];
            v += __shfl_xor(v, 16);
            v += __shfl_xor(v, 32);
            if (quad == 0) atomicAdd(&ng[basehs + nt * 16 + l16], v);
        }
    }
}

// ================= Round-1 fallback path (unchanged, known-correct) =================

__global__ void msfe_prep(const float* __restrict__ Wx, const float* __restrict__ bx,
                          const float* __restrict__ Wfx,
                          const float* __restrict__ Wslice, const float* __restrict__ bslice,
                          unsigned short* __restrict__ Wt, float* __restrict__ bc) {
    int j = blockIdx.x;
    int c = threadIdx.x;
    if (j < 512) {
        int h = j >> 6, s = j & 63;
        float acc = 0.f;
        #pragma unroll 8
        for (int d = 0; d < 64; ++d)
            acc += Wx[c * 512 + h * 64 + d] * Wslice[d * 64 + s];
        Wt[j * 256 + c] = f2bf(acc);
        if (c == 0) {
            float b = bslice[s];
            for (int d = 0; d < 64; ++d) b += bx[h * 64 + d] * Wslice[d * 64 + s];
            bc[j] = b;
        }
    } else {
        int col = j - 512;
        Wt[j * 256 + c] = f2bf(Wfx[c * 512 + col]);
    }
}

__global__ __launch_bounds__(512, 2)
void msfe_main(const float* __restrict__ x,
               const unsigned short* __restrict__ Wt,
               const float* __restrict__ bc,
               const float* __restrict__ bfx,
               const float* __restrict__ temperature,
               float* __restrict__ Tg, float* __restrict__ ng) {
    __shared__ unsigned short Ws[128 * WPITCH];
    __shared__ unsigned short Xs[64 * WPITCH];
    __shared__ unsigned short wT[64 * TPITCH];
    __shared__ unsigned short fT[64 * TPITCH];

    const int tid  = threadIdx.x;
    const int lane = tid & 63;
    const int wv   = tid >> 6;
    const int quad = lane >> 4;
    const int l16  = lane & 15;

    const int bidx = blockIdx.x;
    const int c8   = bidx & 7;
    const int ti   = (bidx >> 3) & 3;
    const int head = (bidx >> 5) & 7;
    const int rnd  = bidx >> 8;
    const int tile = rnd * 32 + c8 * 4 + ti;
    const int batch = tile >> 7;
    const long tok0 = (long)tile * 512;

    {
        int r = tid & 127;
        int part = tid >> 7;
        int grow = (r < 64) ? (head * 64 + r) : (512 + head * 64 + (r - 64));
        const short4v* src = (const short4v*)(Wt + grow * 256 + part * 64);
        short4v* dst = (short4v*)(Ws + r * WPITCH + part * 64);
        #pragma unroll
        for (int j = 0; j < 16; ++j) dst[j] = src[j];
    }
    {
        const float4v* xg = (const float4v*)(x + tok0 * 256);
        #pragma unroll
        for (int i = 0; i < 8; ++i) {
            float4v v = xg[tid + i * 512];
            int f = (tid + i * 512) * 4;
            int trow = f >> 8, col = f & 255;
            short4v p;
            p.x = (short)f2bf(v.x); p.y = (short)f2bf(v.y);
            p.z = (short)f2bf(v.z); p.w = (short)f2bf(v.w);
            *(short4v*)(Xs + trow * WPITCH + col) = p;
        }
    }

    float bcr[4], bfxr[4];
    #pragma unroll
    for (int nt = 0; nt < 4; ++nt) {
        bcr[nt]  = bc [head * 64 + nt * 16 + l16];
        bfxr[nt] = bfx[head * 64 + nt * 16 + l16];
    }
    float tmp = temperature[head];
    tmp = fminf(fmaxf(tmp, 0.5f), 5.0f);
    const float invt = 1.0f / tmp;

    float4v Tac[2];
    Tac[0] = (float4v){0.f, 0.f, 0.f, 0.f};
    Tac[1] = (float4v){0.f, 0.f, 0.f, 0.f};
    float normAcc[4] = {0.f, 0.f, 0.f, 0.f};

    const int proj = wv >> 2;
    const int tw   = wv & 3;
    const int sh   = wv & 3;
    const int dh   = wv >> 2;

    __syncthreads();

    for (int c = 0; c < 8; ++c) {
        float4v xr[8];
        if (c < 7) {
            const float4v* xg = (const float4v*)(x + (tok0 + (long)(c + 1) * 64) * 256);
            #pragma unroll
            for (int i = 0; i < 8; ++i) xr[i] = xg[tid + i * 512];
        }

        float4v acc[4];
        #pragma unroll
        for (int nt = 0; nt < 4; ++nt) acc[nt] = (float4v){0.f, 0.f, 0.f, 0.f};
        #pragma unroll
        for (int ks = 0; ks < 8; ++ks) {
            short8 a = *(const short8*)(Xs + (tw * 16 + l16) * WPITCH + ks * 32 + quad * 8);
            #pragma unroll
            for (int nt = 0; nt < 4; ++nt) {
                short8 b = *(const short8*)(Ws + (proj * 64 + nt * 16 + l16) * WPITCH + ks * 32 + quad * 8);
                acc[nt] = __builtin_amdgcn_mfma_f32_16x16x32_bf16(a, b, acc[nt], 0, 0, 0);
            }
        }

        if (proj == 0) {
            float v[4][4];
            #pragma unroll
            for (int nt = 0; nt < 4; ++nt)
                #pragma unroll
                for (int r = 0; r < 4; ++r)
                    v[nt][r] = (acc[nt][r] + bcr[nt]) * invt;
            #pragma unroll
            for (int r = 0; r < 4; ++r) {
                float m = fmaxf(fmaxf(v[0][r], v[1][r]), fmaxf(v[2][r], v[3][r]));
                m = fmaxf(m, __shfl_xor(m, 1));
                m = fmaxf(m, __shfl_xor(m, 2));
                m = fmaxf(m, __shfl_xor(m, 4));
                m = fmaxf(m, __shfl_xor(m, 8));
                float e0 = __expf(v[0][r] - m), e1 = __expf(v[1][r] - m);
                float e2 = __expf(v[2][r] - m), e3 = __expf(v[3][r] - m);
                float s = e0 + e1 + e2 + e3;
                s += __shfl_xor(s, 1); s += __shfl_xor(s, 2);
                s += __shfl_xor(s, 4); s += __shfl_xor(s, 8);
                float inv = 1.0f / s;
                v[0][r] = e0 * inv; v[1][r] = e1 * inv; v[2][r] = e2 * inv; v[3][r] = e3 * inv;
            }
            #pragma unroll
            for (int nt = 0; nt < 4; ++nt) {
                normAcc[nt] += v[nt][0] + v[nt][1] + v[nt][2] + v[nt][3];
                short4v p;
                p.x = (short)f2bf(v[nt][0]); p.y = (short)f2bf(v[nt][1]);
                p.z = (short)f2bf(v[nt][2]); p.w = (short)f2bf(v[nt][3]);
                *(short4v*)(wT + (nt * 16 + l16) * TPITCH + tw * 16 + quad * 4) = p;
            }
        } else {
            #pragma unroll
            for (int nt = 0; nt < 4; ++nt) {
                short4v p;
                p.x = (short)f2bf(acc[nt][0] + bfxr[nt]);
                p.y = (short)f2bf(acc[nt][1] + bfxr[nt]);
                p.z = (short)f2bf(acc[nt][2] + bfxr[nt]);
                p.w = (short)f2bf(acc[nt][3] + bfxr[nt]);
                *(short4v*)(fT + (nt * 16 + l16) * TPITCH + tw * 16 + quad * 4) = p;
            }
        }

        __syncthreads();

        #pragma unroll
        for (int ks = 0; ks < 2; ++ks) {
            short8 a = *(const short8*)(wT + (sh * 16 + l16) * TPITCH + ks * 32 + quad * 8);
            #pragma unroll
            for (int nt = 0; nt < 2; ++nt) {
                short8 b = *(const short8*)(fT + (dh * 32 + nt * 16 + l16) * TPITCH + ks * 32 + quad * 8);
                Tac[nt] = __builtin_amdgcn_mfma_f32_16x16x32_bf16(a, b, Tac[nt], 0, 0, 0);
            }
        }

        if (c < 7) {
            #pragma unroll
            for (int i = 0; i < 8; ++i) {
                int f = tid * 4 + i * 2048;
                int trow = f >> 8, col = f & 255;
                short4v p;
                p.x = (short)f2bf(xr[i].x); p.y = (short)f2bf(xr[i].y);
                p.z = (short)f2bf(xr[i].z); p.w = (short)f2bf(xr[i].w);
                *(short4v*)(Xs + trow * WPITCH + col) = p;
            }
        }
        __syncthreads();
    }

    const int basehs = (batch * 8 + head) * 64;
    #pragma unroll
    for (int nt = 0; nt < 2; ++nt) {
        #pragma unroll
        for (int r = 0; r < 4; ++r) {
            int s = sh * 16 + quad * 4 + r;
            int d = dh * 32 + nt * 16 + l16;
            atomicAdd(&Tg[(basehs + s) * 64 + d], Tac[nt][r]);
        }
    }
    if (wv < 4) {
        #pragma unroll
        for (int nt = 0; nt < 4; ++nt) {
            float v = normAcc[nt];
            v += __shfl_xor(v, 16);
            v += __shfl_xor(v, 32);
            if (quad == 0) atomicAdd(&ng[basehs + nt * 16 + l16], v);
        }
    }
}

// ---------------- finalize ----------------
__global__ void msfe_final(const float* __restrict__ Tg, const float* __restrict__ ng,
                           float* __restrict__ out) {
    int i = blockIdx.x * 256 + threadIdx.x;
    out[i] = Tg[i] / (ng[i >> 6] + 0.01f);
}

extern "C" void kernel_launch(void* const* d_in, const int* in_sizes, int n_in,
                              void* d_out, int out_size, void* d_ws, size_t ws_size,
                              hipStream_t stream) {
    const float* x       = (const float*)d_in[0];
    const float* Wx      = (const float*)d_in[1];
    const float* bx      = (const float*)d_in[2];
    const float* Wfx     = (const float*)d_in[3];
    const float* bfx     = (const float*)d_in[4];
    const float* Wslice  = (const float*)d_in[5];
    const float* bslice  = (const float*)d_in[6];
    const float* temp    = (const float*)d_in[7];

    char* ws = (char*)d_ws;
    const size_t NEED = 67901440;   // xf 64MB + WtF 512KB + bc 2KB + Tg 256KB + ng 4KB

    if (ws_size >= NEED) {
        unsigned short* xf  = (unsigned short*)ws;               // 67,108,864 B
        unsigned short* WtF = (unsigned short*)(ws + 67108864);  //    524,288 B
        float* bc = (float*)(ws + 67633152);                     //      2,048 B
        float* Tg = (float*)(ws + 67635200);                     //    262,144 B
        float* ng = (float*)(ws + 67897344);                     //      4,096 B

        hipMemsetAsync(Tg, 0, 262144 + 4096, stream);
        msfe_prep2<<<65, 256, 0, stream>>>(Wx, bx, Wfx, Wslice, bslice, WtF, bc);
        msfe_xprep<<<2048, 256, 0, stream>>>(x, xf);
        msfe_main2<<<2048, 512, 0, stream>>>(xf, WtF, bc, bfx, temp, Tg, ng);
        msfe_final<<<256, 256, 0, stream>>>(Tg, ng, (float*)d_out);
    } else {
        unsigned short* Wt = (unsigned short*)ws;       // 524,288 B
        float* bc = (float*)(ws + 524288);
        float* Tg = (float*)(ws + 526336);
        float* ng = (float*)(ws + 788480);

        hipMemsetAsync(Tg, 0, 262144 + 4096, stream);
        msfe_prep<<<1024, 256, 0, stream>>>(Wx, bx, Wfx, Wslice, bslice, Wt, bc);
        msfe_main<<<2048, 512, 0, stream>>>(x, Wt, bc, bfx, temp, Tg, ng);
        msfe_final<<<256, 256, 0, stream>>>(Tg, ng, (float*)d_out);
    }
}